// Round 1
// baseline (1659.438 us; speedup 1.0000x reference)
//
#include <hip/hip_runtime.h>
#include <hip/hip_bf16.h>
#include <math.h>

#define N_NODES 40000
#define N_EDGES 320000
#define HDIM 128
#define T_ITERS 3
#define ACAP 256   // per-node alpha LDS cache (deg ~Poisson(8); fallback recompute path beyond)

typedef __attribute__((ext_vector_type(8))) short short8;
typedef __attribute__((ext_vector_type(4))) short short4v;
typedef __attribute__((ext_vector_type(4))) float f32x4;

static __device__ __forceinline__ short f2bf(float f) {
    union { float f; unsigned u; } x; x.f = f;
    unsigned r = (x.u + 0x7fffu + ((x.u >> 16) & 1u)) >> 16;
    return (short)r;
}
static __device__ __forceinline__ float bf2f(short s) {
    union { unsigned u; float f; } x; x.u = ((unsigned)(unsigned short)s) << 16;
    return x.f;
}

// ---------------------------------------------------------------------------
// Generic MFMA GEMM: C[M,NC] = act(A[M,K] @ W[NC,K]^T + bias + res)
// A fp32 (optionally row-gathered), W bf16, C fp32 or bf16.
// Block: 256 thr = 4 waves; tile 64(M) x 128(N); BK=32.
// ---------------------------------------------------------------------------
template<int ACT, bool OUT_BF16>
__global__ __launch_bounds__(256) void gemm_kernel(
    const float* __restrict__ A, const short* __restrict__ W,
    const float* __restrict__ bias, const float* __restrict__ res,
    float* __restrict__ C, short* __restrict__ Cb,
    const int* __restrict__ row_idx, int M, int K, int NC)
{
    __shared__ short As[64 * 40];   // +8 pad breaks bank conflicts
    __shared__ short Ws[128 * 40];
    const int tid  = threadIdx.x;
    const int lane = tid & 63, wid = tid >> 6;
    const int wm = wid & 1, wn = wid >> 1;
    const int t16 = lane & 15, quad = lane >> 4;
    const long blockM = (long)blockIdx.x * 64;
    const int colBase = blockIdx.y * 128;

    f32x4 acc[2][4];
    for (int i = 0; i < 2; i++)
        for (int j = 0; j < 4; j++)
            acc[i][j] = (f32x4){0.f, 0.f, 0.f, 0.f};

    const int ar_r = tid >> 3;          // 0..31
    const int ar_c = (tid & 7) * 4;     // 0,4,..28
    const int wr   = tid >> 1;          // 0..127
    const int wc   = (tid & 1) * 16;    // 0 or 16

    for (int k0 = 0; k0 < K; k0 += 32) {
        for (int g = 0; g < 2; g++) {
            int r = ar_r + g * 32;
            long gr = blockM + r;
            long srow;
            if (gr < M) srow = row_idx ? (long)row_idx[gr] : gr;
            else        srow = 0;  // safe dummy, result row not stored
            const float4 v = *(const float4*)(A + srow * K + k0 + ar_c);
            short4v sv;
            sv.x = f2bf(v.x); sv.y = f2bf(v.y); sv.z = f2bf(v.z); sv.w = f2bf(v.w);
            *(short4v*)&As[r * 40 + ar_c] = sv;
        }
        {
            const short* wp = W + (long)(colBase + wr) * K + k0 + wc;
            short8 w0 = *(const short8*)wp;
            short8 w1 = *(const short8*)(wp + 8);
            *(short8*)&Ws[wr * 40 + wc]     = w0;
            *(short8*)&Ws[wr * 40 + wc + 8] = w1;
        }
        __syncthreads();
        short8 bfr[4];
        for (int ni = 0; ni < 4; ni++)
            bfr[ni] = *(const short8*)&Ws[(wn * 64 + ni * 16 + t16) * 40 + quad * 8];
        for (int mi = 0; mi < 2; mi++) {
            short8 afr = *(const short8*)&As[(wm * 32 + mi * 16 + t16) * 40 + quad * 8];
            for (int ni = 0; ni < 4; ni++)
                acc[mi][ni] = __builtin_amdgcn_mfma_f32_16x16x32_bf16(
                    afr, bfr[ni], acc[mi][ni], 0, 0, 0);
        }
        __syncthreads();
    }

    for (int mi = 0; mi < 2; mi++)
        for (int ni = 0; ni < 4; ni++) {
            int gc = colBase + wn * 64 + ni * 16 + t16;
            for (int r = 0; r < 4; r++) {
                long gr = blockM + wm * 32 + mi * 16 + quad * 4 + r;
                if (gr < M) {
                    float v = acc[mi][ni][r];
                    if (bias) v += bias[gc];
                    if (res)  v += res[gr * NC + gc];
                    if (ACT == 1) v = 0.5f * v * (1.0f + erff(v * 0.70710678118654752f));
                    if (OUT_BF16) Cb[gr * (long)NC + gc] = f2bf(v);
                    else          C [gr * (long)NC + gc] = v;
                }
            }
        }
}

// ---------------------------------------------------------------------------
// CSR build
// ---------------------------------------------------------------------------
__global__ void count_kernel(const int* __restrict__ dst, int* __restrict__ cnt) {
    int e = blockIdx.x * 256 + threadIdx.x;
    if (e < N_EDGES) atomicAdd(&cnt[dst[e]], 1);
}

__global__ __launch_bounds__(1024) void scan_kernel(const int* __restrict__ cnt,
                                                    int* __restrict__ rowptr) {
    __shared__ int lds[1024];
    const int tid = threadIdx.x;
    const int CH = 40;                 // 1024*40 = 40960 >= 40000
    const int base = tid * CH;
    int sum = 0;
    for (int j = 0; j < CH; j++) { int i = base + j; if (i < N_NODES) sum += cnt[i]; }
    lds[tid] = sum;
    __syncthreads();
    for (int off = 1; off < 1024; off <<= 1) {
        int v = (tid >= off) ? lds[tid - off] : 0;
        __syncthreads();
        lds[tid] += v;
        __syncthreads();
    }
    int run = lds[tid] - sum;          // exclusive prefix of this chunk
    for (int j = 0; j < CH; j++) {
        int i = base + j;
        if (i < N_NODES) { rowptr[i] = run; run += cnt[i]; }
    }
    if (tid == 1023) rowptr[N_NODES] = lds[1023];
}

__global__ void fill_kernel(const int* __restrict__ src, const int* __restrict__ dst,
                            const int* __restrict__ rowptr, int* __restrict__ wo,
                            int* __restrict__ perm, int* __restrict__ srcp) {
    int e = blockIdx.x * 256 + threadIdx.x;
    if (e < N_EDGES) {
        int d = dst[e];
        int pos = atomicAdd(&wo[d], 1);
        int slot = rowptr[d] + pos;
        perm[slot] = e;
        srcp[slot] = src[e];
    }
}

// ---------------------------------------------------------------------------
// Edge attention: one wave per dst node. QKV [N,384], EKp/EVp bf16 [E,128]
// (bias folded, CSR-permuted). Softmax alphas cached in LDS (cap ACAP).
// ---------------------------------------------------------------------------
__global__ __launch_bounds__(256) void edge_attn_kernel(
    const float* __restrict__ QKV, const short* __restrict__ EKp,
    const short* __restrict__ EVp, const int* __restrict__ rowptr,
    const int* __restrict__ srcp, float* __restrict__ out)
{
    __shared__ float alds[4 * 4 * ACAP];
    const int wid = threadIdx.x >> 6, lane = threadIdx.x & 63;
    const int n = blockIdx.x * 4 + wid;
    if (n >= N_NODES) return;
    const int head = lane >> 4, t16 = lane & 15;
    const int d0 = head * 32 + t16 * 2;
    float* aw = &alds[(wid * 4 + head) * ACAP];

    const float2 q = *(const float2*)&QKV[(long)n * 384 + d0];
    const int beg = rowptr[n], end = rowptr[n + 1];
    const float scale = 0.17677669529663687f;   // 1/sqrt(32)

    float m = -1e30f;
    for (int i = beg; i < end; i++) {
        int s = srcp[i];
        unsigned ek = *(const unsigned*)&EKp[(long)i * 128 + d0];
        float2 xk = *(const float2*)&QKV[(long)s * 384 + 128 + d0];
        float k0 = xk.x + bf2f((short)(ek & 0xffff));
        float k1 = xk.y + bf2f((short)(ek >> 16));
        float p = q.x * k0 + q.y * k1;
        p += __shfl_xor(p, 1); p += __shfl_xor(p, 2);
        p += __shfl_xor(p, 4); p += __shfl_xor(p, 8);
        float alpha = p * scale;
        int j = i - beg;
        if (j < ACAP && t16 == 0) aw[j] = alpha;
        m = fmaxf(m, alpha);
    }

    float acc0 = 0.f, acc1 = 0.f, ssum = 0.f;
    for (int i = beg; i < end; i++) {
        int s = srcp[i];
        int j = i - beg;
        float alpha;
        if (j < ACAP) {
            alpha = aw[j];
        } else {  // ultra-rare fallback: recompute
            unsigned ek = *(const unsigned*)&EKp[(long)i * 128 + d0];
            float2 xk = *(const float2*)&QKV[(long)s * 384 + 128 + d0];
            float k0 = xk.x + bf2f((short)(ek & 0xffff));
            float k1 = xk.y + bf2f((short)(ek >> 16));
            float p = q.x * k0 + q.y * k1;
            p += __shfl_xor(p, 1); p += __shfl_xor(p, 2);
            p += __shfl_xor(p, 4); p += __shfl_xor(p, 8);
            alpha = p * scale;
        }
        float a = __expf(alpha - m);
        ssum += a;
        unsigned ev = *(const unsigned*)&EVp[(long)i * 128 + d0];
        float2 xv = *(const float2*)&QKV[(long)s * 384 + 256 + d0];
        acc0 += a * (xv.x + bf2f((short)(ev & 0xffff)));
        acc1 += a * (xv.y + bf2f((short)(ev >> 16)));
    }
    float inv = 1.0f / (ssum + 1e-16f);
    float2 o; o.x = acc0 * inv; o.y = acc1 * inv;
    *(float2*)&out[(long)n * 128 + d0] = o;
}

// ---------------------------------------------------------------------------
// LayerNorm over rows of 128: one wave per row
// ---------------------------------------------------------------------------
__global__ __launch_bounds__(256) void ln_kernel(
    const float* __restrict__ X, const float* __restrict__ g,
    const float* __restrict__ b, float* __restrict__ Y)
{
    const int wid = threadIdx.x >> 6, lane = threadIdx.x & 63;
    const long n = (long)blockIdx.x * 4 + wid;
    if (n >= N_NODES) return;
    float2 v = *(const float2*)&X[n * 128 + lane * 2];
    float s = v.x + v.y;
    for (int o = 1; o < 64; o <<= 1) s += __shfl_xor(s, o);
    float u = s * (1.0f / 128.0f);
    float dx = v.x - u, dy = v.y - u;
    float vs = dx * dx + dy * dy;
    for (int o = 1; o < 64; o <<= 1) vs += __shfl_xor(vs, o);
    float rstd = rsqrtf(vs * (1.0f / 128.0f) + 1e-12f);
    float2 gg = *(const float2*)&g[lane * 2];
    float2 bb = *(const float2*)&b[lane * 2];
    float2 o2; o2.x = gg.x * dx * rstd + bb.x; o2.y = gg.y * dy * rstd + bb.y;
    *(float2*)&Y[n * 128 + lane * 2] = o2;
}

// ---------------------------------------------------------------------------
// GRU gates + hidden update + LN3, one wave per row
// ---------------------------------------------------------------------------
__global__ __launch_bounds__(256) void gru_ln_kernel(
    const float* __restrict__ gi, const float* __restrict__ gh,
    const float* __restrict__ hin, const float* __restrict__ g,
    const float* __restrict__ b, float* __restrict__ hout,
    float* __restrict__ xout)
{
    const int wid = threadIdx.x >> 6, lane = threadIdx.x & 63;
    const long n = (long)blockIdx.x * 4 + wid;
    if (n >= N_NODES) return;
    const long gb = n * 384 + lane * 2;
    const long hb = n * 128 + lane * 2;
    float2 ir = *(const float2*)&gi[gb];
    float2 iz = *(const float2*)&gi[gb + 128];
    float2 in_ = *(const float2*)&gi[gb + 256];
    float2 hr = *(const float2*)&gh[gb];
    float2 hz = *(const float2*)&gh[gb + 128];
    float2 hn = *(const float2*)&gh[gb + 256];
    float2 hp = *(const float2*)&hin[hb];
    float r0 = 1.f / (1.f + __expf(-(ir.x + hr.x)));
    float r1 = 1.f / (1.f + __expf(-(ir.y + hr.y)));
    float z0 = 1.f / (1.f + __expf(-(iz.x + hz.x)));
    float z1 = 1.f / (1.f + __expf(-(iz.y + hz.y)));
    float n0 = tanhf(in_.x + r0 * hn.x);
    float n1 = tanhf(in_.y + r1 * hn.y);
    float h0 = (1.f - z0) * n0 + z0 * hp.x;
    float h1 = (1.f - z1) * n1 + z1 * hp.y;
    float s = h0 + h1;
    for (int o = 1; o < 64; o <<= 1) s += __shfl_xor(s, o);
    float u = s * (1.0f / 128.0f);
    float d0 = h0 - u, d1 = h1 - u;
    float vs = d0 * d0 + d1 * d1;
    for (int o = 1; o < 64; o <<= 1) vs += __shfl_xor(vs, o);
    float rstd = rsqrtf(vs * (1.0f / 128.0f) + 1e-12f);
    float2 gg = *(const float2*)&g[lane * 2];
    float2 bb = *(const float2*)&b[lane * 2];
    float2 ho; ho.x = h0; ho.y = h1;
    *(float2*)&hout[hb] = ho;
    float2 xo; xo.x = gg.x * d0 * rstd + bb.x; xo.y = gg.y * d1 * rstd + bb.y;
    *(float2*)&xout[hb] = xo;
}

// ---------------------------------------------------------------------------
// Small helpers
// ---------------------------------------------------------------------------
__global__ void cvt_kernel(const float* __restrict__ s, short* __restrict__ d, int n) {
    int i = blockIdx.x * 256 + threadIdx.x;
    if (i < n) d[i] = f2bf(s[i]);
}
__global__ void bqkv_kernel(const float* __restrict__ bq, float* __restrict__ bqkv) {
    int i = blockIdx.x * 256 + threadIdx.x;
    if (i < 384) bqkv[i] = (i < 128) ? bq[i] : 0.0f;
}

// ---------------------------------------------------------------------------
extern "C" void kernel_launch(void* const* d_in, const int* in_sizes, int n_in,
                              void* d_out, int out_size, void* d_ws, size_t ws_size,
                              hipStream_t stream) {
    const float* x_in  = (const float*)d_in[0];
    const int*   eidx  = (const int*)d_in[1];
    const float* ea    = (const float*)d_in[2];
    const float* wq    = (const float*)d_in[3];
    const float* bq    = (const float*)d_in[4];
    const float* wk    = (const float*)d_in[5];
    const float* bk    = (const float*)d_in[6];
    const float* wv    = (const float*)d_in[7];
    const float* bv    = (const float*)d_in[8];
    const float* w_ao  = (const float*)d_in[9];
    const float* b_ao  = (const float*)d_in[10];
    const float* ln1_g = (const float*)d_in[11];
    const float* ln1_b = (const float*)d_in[12];
    const float* w_int = (const float*)d_in[13];
    const float* b_int = (const float*)d_in[14];
    const float* w_out = (const float*)d_in[15];
    const float* b_out = (const float*)d_in[16];
    const float* ln2_g = (const float*)d_in[17];
    const float* ln2_b = (const float*)d_in[18];
    const float* w_ih  = (const float*)d_in[19];
    const float* w_hh  = (const float*)d_in[20];
    const float* b_ih  = (const float*)d_in[21];
    const float* b_hh  = (const float*)d_in[22];
    const float* ln3_g = (const float*)d_in[23];
    const float* ln3_b = (const float*)d_in[24];
    const int* srcv = eidx;
    const int* dstv = eidx + N_EDGES;

    char* ws = (char*)d_ws;
    size_t off = 0;
    auto alloc = [&](size_t bytes) -> void* {
        void* p = ws + off;
        off += (bytes + 255) & ~(size_t)255;
        return p;
    };
    short* EKp  = (short*)alloc((size_t)N_EDGES * 128 * 2);
    short* EVp  = (short*)alloc((size_t)N_EDGES * 128 * 2);
    short* Wcat = (short*)alloc(384 * 128 * 2);   // [wq;wk;wv]
    short* Wao  = (short*)alloc(128 * 128 * 2);
    short* Wint = (short*)alloc(512 * 128 * 2);
    short* Wout = (short*)alloc(128 * 512 * 2);
    short* Wih  = (short*)alloc(384 * 128 * 2);
    short* Whh  = (short*)alloc(384 * 128 * 2);
    float* bqkv = (float*)alloc(384 * 4);
    int* cnt    = (int*)alloc((size_t)N_NODES * 4);
    int* wo     = (int*)alloc((size_t)N_NODES * 4);
    int* rowptr = (int*)alloc((size_t)(N_NODES + 1) * 4);
    int* perm   = (int*)alloc((size_t)N_EDGES * 4);
    int* srcp   = (int*)alloc((size_t)N_EDGES * 4);
    float* QKV    = (float*)alloc((size_t)N_NODES * 384 * 4);  // reused as gi
    float* attraw = (float*)alloc((size_t)N_NODES * 128 * 4);  // reused as m_
    float* t1     = (float*)alloc((size_t)N_NODES * 128 * 4);  // reused as t2
    float* att    = (float*)alloc((size_t)N_NODES * 128 * 4);
    float* inter  = (float*)alloc((size_t)N_NODES * 512 * 4);  // reused as gh
    float* hbuf   = (float*)alloc((size_t)N_NODES * 128 * 4);
    float* xbuf   = (float*)alloc((size_t)N_NODES * 128 * 4);
    if (off > ws_size) return;  // workspace too small: fail loudly via wrong output

    // --- weight conversion (once per call) ---
    cvt_kernel<<<64, 256, 0, stream>>>(wq, Wcat, 16384);
    cvt_kernel<<<64, 256, 0, stream>>>(wk, Wcat + 16384, 16384);
    cvt_kernel<<<64, 256, 0, stream>>>(wv, Wcat + 32768, 16384);
    cvt_kernel<<<64, 256, 0, stream>>>(w_ao, Wao, 16384);
    cvt_kernel<<<256, 256, 0, stream>>>(w_int, Wint, 65536);
    cvt_kernel<<<256, 256, 0, stream>>>(w_out, Wout, 65536);
    cvt_kernel<<<192, 256, 0, stream>>>(w_ih, Wih, 49152);
    cvt_kernel<<<192, 256, 0, stream>>>(w_hh, Whh, 49152);
    bqkv_kernel<<<2, 256, 0, stream>>>(bq, bqkv);

    // --- CSR by dst ---
    hipMemsetAsync(cnt, 0, (size_t)N_NODES * 4, stream);
    hipMemsetAsync(wo, 0, (size_t)N_NODES * 4, stream);
    count_kernel<<<1250, 256, 0, stream>>>(dstv, cnt);
    scan_kernel<<<1, 1024, 0, stream>>>(cnt, rowptr);
    fill_kernel<<<1250, 256, 0, stream>>>(srcv, dstv, rowptr, wo, perm, srcp);

    // --- EK/EV precompute (CSR-permuted, bias folded, bf16 out) ---
    gemm_kernel<0, true><<<dim3(5000, 1), 256, 0, stream>>>(
        ea, Wcat + 128 * 128, bk, nullptr, nullptr, EKp, perm, N_EDGES, 128, 128);
    gemm_kernel<0, true><<<dim3(5000, 1), 256, 0, stream>>>(
        ea, Wcat + 256 * 128, bv, nullptr, nullptr, EVp, perm, N_EDGES, 128, 128);

    const float* xcur = x_in;
    const float* hcur = x_in;
    for (int t = 0; t < T_ITERS; t++) {
        // QKV = x @ [wq;wk;wv]^T + [bq;0;0]
        gemm_kernel<0, false><<<dim3(625, 3), 256, 0, stream>>>(
            xcur, Wcat, bqkv, nullptr, QKV, nullptr, nullptr, N_NODES, 128, 384);
        // GAT attention
        edge_attn_kernel<<<10000, 256, 0, stream>>>(QKV, EKp, EVp, rowptr, srcp, attraw);
        // t1 = attraw @ w_ao^T + b_ao + x ; att = LN1(t1)
        gemm_kernel<0, false><<<dim3(625, 1), 256, 0, stream>>>(
            attraw, Wao, b_ao, xcur, t1, nullptr, nullptr, N_NODES, 128, 128);
        ln_kernel<<<10000, 256, 0, stream>>>(t1, ln1_g, ln1_b, att);
        // inter = gelu(att @ w_int^T + b_int)
        gemm_kernel<1, false><<<dim3(625, 4), 256, 0, stream>>>(
            att, Wint, b_int, nullptr, inter, nullptr, nullptr, N_NODES, 128, 512);
        // t2 = inter @ w_out^T + b_out + att ; m = LN2(t2)  (t2 -> t1 buf, m -> attraw buf)
        gemm_kernel<0, false><<<dim3(625, 1), 256, 0, stream>>>(
            inter, Wout, b_out, att, t1, nullptr, nullptr, N_NODES, 512, 128);
        ln_kernel<<<10000, 256, 0, stream>>>(t1, ln2_g, ln2_b, attraw);
        // gi = m @ w_ih^T + b_ih (-> QKV buf); gh = h @ w_hh^T + b_hh (-> inter buf)
        gemm_kernel<0, false><<<dim3(625, 3), 256, 0, stream>>>(
            attraw, Wih, b_ih, nullptr, QKV, nullptr, nullptr, N_NODES, 128, 384);
        gemm_kernel<0, false><<<dim3(625, 3), 256, 0, stream>>>(
            hcur, Whh, b_hh, nullptr, inter, nullptr, nullptr, N_NODES, 128, 384);
        // GRU + LN3
        float* xdst = (t == T_ITERS - 1) ? (float*)d_out : xbuf;
        gru_ln_kernel<<<10000, 256, 0, stream>>>(QKV, inter, hcur, ln3_g, ln3_b, hbuf, xdst);
        xcur = xbuf;
        hcur = hbuf;
    }
}